// Round 6
// baseline (1111.409 us; speedup 1.0000x reference)
//
#include <hip/hip_runtime.h>
#include <hip/hip_bf16.h>

typedef unsigned char u8;
typedef unsigned short u16;
typedef __attribute__((ext_vector_type(8))) short bf16x8;
typedef __attribute__((ext_vector_type(8))) _Float16 f16x8;
typedef __attribute__((ext_vector_type(4))) float f32x4;
typedef __attribute__((ext_vector_type(2))) float f32x2;
typedef __attribute__((ext_vector_type(4))) int i32x4;

#define T_ 128
#define B_ 32
#define I_ 128
#define H_ 128
#define R_ 100
#define O_ 64
#define NWG2 200              /* (region, batch-half) workgroups */
#define NRED 4                /* dedicated reducer WGs (small mode only) */
#define SLICE (R_*B_*H_)      /* bytes per fp8 H slice */
#define ROWB  (B_*H_)         /* 4096 bytes per region row in a slice */
#define XOFF  (T_*B_*I_)
#define WOFF  (R_*H_*H_)
#define OOFF  (O_*R_*H_)
#define PB    (16*O_)         /* small-mode part floats per WG slot */

__device__ __forceinline__ float b2f(u16 u) {
  unsigned x = ((unsigned)u) << 16; float f; __builtin_memcpy(&f, &x, 4); return f;
}
__device__ __forceinline__ u16 f2b(float f) {
  unsigned x; __builtin_memcpy(&x, &f, 4);
  unsigned lsb = (x >> 16) & 1u;
  x += 0x7fffu + lsb;
  return (u16)(x >> 16);
}
__device__ __forceinline__ void split2(float f, u16& hi, u16& lo) {
  hi = f2b(f);
  lo = f2b(f - b2f(hi));
}
__device__ __forceinline__ u16 f2h(float f) {
  _Float16 h = (_Float16)f; u16 u; __builtin_memcpy(&u, &h, 2); return u;
}
__device__ __forceinline__ float h2f(u16 u) {
  _Float16 h; __builtin_memcpy(&h, &u, 2); return (float)h;
}
__device__ __forceinline__ void split2h(float f, u16& hi, u16& lo) {
  _Float16 h = (_Float16)f;
  _Float16 l = (_Float16)(f - (float)h);
  __builtin_memcpy(&hi, &h, 2); __builtin_memcpy(&lo, &l, 2);
}
__device__ __forceinline__ float fast_tanh(float v) {
  float a = fabsf(v);
  float e = __expf(-2.f * a);
  float th = (1.f - e) * __builtin_amdgcn_rcpf(1.f + e);
  return v < 0.f ? -th : th;
}

// ---------------- fp8 e4m3 pack/unpack (HW builtin or bit-exact manual) ------
#if __has_builtin(__builtin_amdgcn_cvt_pk_f32_fp8) && __has_builtin(__builtin_amdgcn_cvt_pk_fp8_f32)
#define HW_FP8 1
#endif

__device__ __forceinline__ unsigned enc1_fp8(float f) {
  unsigned x; __builtin_memcpy(&x, &f, 4);
  unsigned s = (x >> 31) << 7;
  float a = fabsf(f);
  if (!(a < 464.f)) return s | 0x7E;
  if (a == 0.f) return s;
  int E = (int)((x >> 23) & 0xFF) - 127;
  if (E < -6) E = -6;
  float sc; unsigned sb = (unsigned)(127 + 3 - E) << 23; __builtin_memcpy(&sc, &sb, 4);
  int q = (int)rintf(a * sc);
  if (q == 16) { E += 1; q = 8; }
  if (E > 8) return s | 0x7E;
  unsigned ee, mm;
  if (q < 8) { ee = 0; mm = (unsigned)q; }
  else { ee = (unsigned)(E + 7); mm = (unsigned)(q - 8); }
  return s | (ee << 3) | mm;
}
__device__ __forceinline__ float dec1_fp8(unsigned b) {
  unsigned s = (b >> 7) & 1, ee = (b >> 3) & 0xF, mm = b & 7;
  float v;
  if (ee == 0) v = (float)mm * 0.001953125f;
  else { unsigned fb = ((ee + 120) << 23) | (mm << 20); __builtin_memcpy(&v, &fb, 4); }
  return s ? -v : v;
}
// decode 4 fp8 -> two f32 pairs
__device__ __forceinline__ void fp8x4_to_2x2(unsigned u, f32x2& a, f32x2& b) {
#ifdef HW_FP8
  a = __builtin_amdgcn_cvt_pk_f32_fp8((int)u, false);
  b = __builtin_amdgcn_cvt_pk_f32_fp8((int)u, true);
#else
  a[0] = dec1_fp8(u & 255); a[1] = dec1_fp8((u >> 8) & 255);
  b[0] = dec1_fp8((u >> 16) & 255); b[1] = dec1_fp8(u >> 24);
#endif
}
__device__ __forceinline__ void fp8x4_to_f32(unsigned u, float* o) {
  f32x2 a, b; fp8x4_to_2x2(u, a, b);
  o[0] = a[0]; o[1] = a[1]; o[2] = b[0]; o[3] = b[1];
}
__device__ __forceinline__ unsigned f32x4_to_fp8(float f0, float f1, float f2, float f3) {
#ifdef HW_FP8
  int v = __builtin_amdgcn_cvt_pk_fp8_f32(f0, f1, 0, false);
  v = __builtin_amdgcn_cvt_pk_fp8_f32(f2, f3, v, true);
  return (unsigned)v;
#else
  return enc1_fp8(f0) | (enc1_fp8(f1) << 8) | (enc1_fp8(f2) << 16) | (enc1_fp8(f3) << 24);
#endif
}
// pack 16 f16 (from LDS) -> 16 fp8 as i32x4
__device__ __forceinline__ i32x4 pack16(const u16* p) {
  i32x4 o;
  #pragma unroll
  for (int g = 0; g < 4; ++g)
    o[g] = (int)f32x4_to_fp8(h2f(p[g*4+0]), h2f(p[g*4+1]), h2f(p[g*4+2]), h2f(p[g*4+3]));
  return o;
}

// packed dual-f32 FMA (CDNA VOP3P): d = a*b + c, element-wise on pairs.
// Same IEEE fma per element as v_fma_f32 -> bit-exact vs the scalar chain.
__device__ __forceinline__ f32x2 pk_fma(f32x2 a, f32x2 b, f32x2 c) {
  f32x2 d;
  asm("v_pk_fma_f32 %0, %1, %2, %3" : "=v"(d) : "v"(a), "v"(b), "v"(c));
  return d;
}

// ---- cache-scope accessors --------------------------------------------------
// sc1 store = agent scope (writes land at LLC).
// sc0 load  = bypass L1, served by local L2 (r4/r5-verified correct under
//             the acquire-agent fence handshake).
__device__ __forceinline__ void st16_sc(void* p, i32x4 v) {
  asm volatile("global_store_dwordx4 %0, %1, off sc1" :: "v"(p), "v"(v) : "memory");
}
// issue-only 4B L2-cached load: NO waitcnt — caller manages vmcnt manually.
__device__ __forceinline__ void ld4_issue0(int& r, const void* p) {
  asm volatile("global_load_dword %0, %1, off sc0" : "=v"(r) : "v"(p));
}
__device__ __forceinline__ void wait_vm() { asm volatile("s_waitcnt vmcnt(0)" ::: "memory"); }
// manual vmcnt wait + scheduling fence (guide rule #18)
#define WAITV(N) do { asm volatile("s_waitcnt vmcnt(" #N ")" ::: "memory"); \
                      __builtin_amdgcn_sched_barrier(0); } while (0)

__device__ __forceinline__ float aldf(const float* p) {
  return __hip_atomic_load((float*)p, __ATOMIC_RELAXED, __HIP_MEMORY_SCOPE_AGENT);
}
__device__ __forceinline__ void astf(float* p, float v) {
  __hip_atomic_store(p, v, __ATOMIC_RELAXED, __HIP_MEMORY_SCOPE_AGENT);
}

// ---- dtype probe ----
__global__ void __launch_bounds__(256)
probe_dtype(const u16* __restrict__ x, int* __restrict__ mode)
{
  __shared__ int cnt;
  if (threadIdx.x == 0) cnt = 0;
  __syncthreads();
  int bad = 0;
  for (int i = threadIdx.x; i < 8192; i += 256) {
    int ex = (x[i] >> 7) & 0xFF;
    if (ex >= 134) ++bad;
  }
  atomicAdd(&cnt, bad);
  __syncthreads();
  if (threadIdx.x == 0) *mode = (cnt > 256) ? 1 : 0;
}

__device__ __forceinline__ float load_in(const void* p, size_t i, int f32) {
  return f32 ? ((const float*)p)[i] : b2f(((const u16*)p)[i]);
}

__global__ void __launch_bounds__(256)
conv_split(const void* __restrict__ src, u16* __restrict__ hi, u16* __restrict__ lo,
           const int* __restrict__ mode, int n)
{
  int i = blockIdx.x * 256 + threadIdx.x;
  if (i < n) { u16 h, l; split2(load_in(src, i, *mode), h, l); hi[i] = h; lo[i] = l; }
}

__global__ void __launch_bounds__(256)
conv_vec(const void* __restrict__ src, float* __restrict__ dst,
         const int* __restrict__ mode, int n)
{
  int i = blockIdx.x * 256 + threadIdx.x;
  if (i < n) dst[i] = load_in(src, i, *mode);
}

// Tiled transpose -> split pair; fmt: 0 = bf16 split, 1 = f16 split
__global__ void __launch_bounds__(256)
transpose_kn2(const void* __restrict__ in, u16* __restrict__ ohi, u16* __restrict__ olo,
              int KK, int NN, const int* __restrict__ mode, int fmt)
{
  __shared__ float tile[32][33];
  const int f32 = *mode;
  int ntk = KK >> 5, ntn = NN >> 5;
  int bid = blockIdx.x;
  int m  = bid / (ntk * ntn);
  int rem = bid % (ntk * ntn);
  int kt = rem / ntn, nt = rem % ntn;
  size_t base = (size_t)m * KK * NN;
  int tid = threadIdx.x;
  int tc = tid & 31, tr0 = tid >> 5;
  #pragma unroll
  for (int rr = 0; rr < 4; ++rr) {
    int tr = tr0 + rr * 8;
    tile[tr][tc] = load_in(in, base + (size_t)(kt*32 + tr) * NN + nt*32 + tc, f32);
  }
  __syncthreads();
  #pragma unroll
  for (int rr = 0; rr < 4; ++rr) {
    int tr = tr0 + rr * 8;
    u16 h, l;
    if (fmt) split2h(tile[tc][tr], h, l); else split2(tile[tc][tr], h, l);
    size_t di = base + (size_t)(nt*32 + tr) * KK + kt*32 + tc;
    ohi[di] = h; olo[di] = l;
  }
}

// Full-barrier wait (small-mode reducer path)
__device__ __forceinline__ void wait_flags(const int* f, int cnt, int target, int tid) {
  if (tid < cnt) {
    int sp = 0;
    while (__hip_atomic_load((int*)&f[tid * 32], __ATOMIC_RELAXED, __HIP_MEMORY_SCOPE_AGENT) < target) {
      __builtin_amdgcn_s_sleep(2);
      if (++sp > (1 << 18)) break;
    }
  }
  asm volatile("" ::: "memory");
  __syncthreads();
}
// Per-thread poll: short hot spin, then backoff
__device__ __forceinline__ void poll1(const int* f, int target) {
  int sp = 0;
  while (__hip_atomic_load((int*)f, __ATOMIC_RELAXED, __HIP_MEMORY_SCOPE_AGENT) < target) {
    if (++sp > 48) __builtin_amdgcn_s_sleep(2);
    if (sp > (1 << 20)) break;
  }
  asm volatile("" ::: "memory");
}
__device__ __forceinline__ void post_flag(int* f, int v) {
  __hip_atomic_store(f, v, __ATOMIC_RELAXED, __HIP_MEMORY_SCOPE_AGENT);
}

__device__ __forceinline__ f32x4 mfma_(bf16x8 a, bf16x8 b, f32x4 c) {
  return __builtin_amdgcn_mfma_f32_16x16x32_bf16(a, b, c, 0, 0, 0);
}
__device__ __forceinline__ f32x4 mfma_h(f16x8 a, f16x8 b, f32x4 c) {
  return __builtin_amdgcn_mfma_f32_16x16x32_f16(a, b, c, 0, 0, 0);
}

// per-row mixing (packed): macc01/macc23 += {C,C} * fp8x4(H row fragment)
// 5 issue slots/row: ds_read_b64 + 2 cvt_pk + 2 v_pk_fma_f32
#define MIXROW(Q, CI) do { \
  f32x2 c2_ = csh2[(CI)]; \
  f32x2 a_, b_; fp8x4_to_2x2((unsigned)(Q), a_, b_); \
  macc01 = pk_fma(a_, c2_, macc01); \
  macc23 = pk_fma(b_, c2_, macc23); \
} while (0)

#define ISSUE8(Q, P) do { _Pragma("unroll") \
  for (int k_ = 0; k_ < 8; ++k_) ld4_issue0(Q[k_], (P) + (size_t)k_ * ROWB); } while (0)
#define ISSUE4(Q, P) do { _Pragma("unroll") \
  for (int k_ = 0; k_ < 4; ++k_) ld4_issue0(Q[k_], (P) + (size_t)k_ * ROWB); } while (0)
#define PROC8(Q, CI) do { _Pragma("unroll") \
  for (int k_ = 0; k_ < 8; ++k_) MIXROW(Q[k_], (CI) + k_); } while (0)
#define PROC4(Q, CI) do { _Pragma("unroll") \
  for (int k_ = 0; k_ < 4; ++k_) MIXROW(Q[k_], (CI) + k_); } while (0)

// Single-hop persistent RNN; weights register-resident; mixing reads H from
// the local XCD L2 (sc0) after a per-WG acquire-agent fence (buffer_inv).
// flags: [w*32] = H-ready gen, [w*32+1] = part-ready (small mode).
__global__ void __launch_bounds__(512, 2)
rnn_kernel(const u16* __restrict__ x,            // split bf16
           u8* __restrict__ Hb,                  // fp8, 2 slices (agent-coherent)
           const u16* __restrict__ WihT, const u16* __restrict__ WhhT,  // split bf16
           const u16* __restrict__ WrhhT,        // split f16
           const float* __restrict__ Cf,         // plain f32 C [R][R]
           const float* __restrict__ biasf,
           const u16* __restrict__ WoutT,        // split bf16
           float* __restrict__ part,             // small mode: 2-buf fp32
           u16* __restrict__ part2,              // big mode: [t][r] bf16 plain
           const float* __restrict__ boutf,
           float* __restrict__ out, int* __restrict__ flags, int bigpart)
{
  const int w    = blockIdx.x;
  const int tid  = threadIdx.x;
  const int lane = tid & 63;
  const int wv   = tid >> 6;          // 0..7
  const int l15  = lane & 15;
  const int quad = lane >> 4;

  __shared__ __align__(16) u16 Hmhi[16 * 136];   // local H state, split bf16
  __shared__ __align__(16) u16 Hmlo[16 * 136];
  __shared__ __align__(16) u16 msgS[16 * 136];   // mixed message, f16
  __shared__ __align__(16) u16 mS[16 * 128];     // H staging f16 for fp8 pack
  __shared__ __align__(16) f32x2 csh2[112];      // {C,C} pairs for this region

  // ---- dedicated reducer WGs (small mode only; grid = 204 then) ----
  if (w >= NWG2) {
    const int aw = w - NWG2;                     // 0..3
    for (int t = 0; t < T_; ++t) {
      wait_flags(flags + 1, NWG2, t + 1, tid);
      const float* pb = part + (size_t)(t & 1) * (NWG2 * PB);
      int e = aw * 512 + tid;                    // 0..2047
      int b = e >> 6, o = e & 63;
      int ue = b >> 4, bl = b & 15;
      float s = 0.f;
      #pragma unroll 4
      for (int r2 = 0; r2 < R_; ++r2)
        s += aldf(pb + (size_t)(r2 * 2 + ue) * PB + bl * O_ + o);
      out[(size_t)t * (B_*O_) + e] = s + boutf[o];
    }
    return;
  }

  const int r = w >> 1;        // region
  const int u = w & 1;         // batch half (rows u*16 .. u*16+15)
  const int col = wv * 16 + l15;   // this thread's N column (0..127)

  for (int e = tid; e < 16 * 136; e += 512) { Hmhi[e] = 0; Hmlo[e] = 0; }
  if (tid < R_) {
    float c = Cf[(size_t)tid * R_ + r];
    f32x2 c2; c2[0] = c; c2[1] = c;
    csh2[tid] = c2;
  }
  __syncthreads();

  // ---- hoist ALL t-invariant per-thread weight fragments into registers ----
  bf16x8 w0h[4], w0l[4], w1h[4], w1l[4];
  f16x8  w2h[4], w2l[4];
  bf16x8 boh[4], bol[4];
  {
    const u16* B0 = WihT  + (size_t)r * (H_*I_) + (size_t)col * 128;
    const u16* B1 = WhhT  + (size_t)r * (H_*H_) + (size_t)col * 128;
    const u16* B2 = WrhhT + (size_t)r * (H_*H_) + (size_t)col * 128;
    const int o = (wv >= 4) ? ((wv - 4) * 16 + l15) : l15;   // dummy for wv<4
    const u16* Bo = WoutT + (size_t)o * (R_*H_) + (size_t)r * H_;
    #pragma unroll
    for (int kk = 0; kk < 4; ++kk) {
      int koff = kk * 32 + quad * 8;
      w0h[kk] = *(const bf16x8*)(B0 + koff);
      w0l[kk] = *(const bf16x8*)(B0 + WOFF + koff);
      w1h[kk] = *(const bf16x8*)(B1 + koff);
      w1l[kk] = *(const bf16x8*)(B1 + WOFF + koff);
      w2h[kk] = *(const f16x8*)(B2 + koff);
      w2l[kk] = *(const f16x8*)(B2 + WOFF + koff);
      boh[kk] = *(const bf16x8*)(Bo + koff);
      bol[kk] = *(const bf16x8*)(Bo + OOFF + koff);
    }
  }
  const float bs = biasf[r*H_ + col];

  for (int t = 0; t < T_; ++t) {
    // ===== seg0 (x @ Wih) + seg1 (local H @ Whh), weights in regs =====
    f32x4 accX = {0,0,0,0}, accH = {0,0,0,0};
    {
      const u16* Ax = x + (size_t)t * (B_*I_) + (size_t)(u*16) * I_;
      #pragma unroll
      for (int kk = 0; kk < 4; ++kk) {
        int koff = kk * 32 + quad * 8;
        const u16* pa = Ax + (size_t)l15 * 128 + koff;
        bf16x8 ah = *(const bf16x8*)pa, al = *(const bf16x8*)(pa + XOFF);
        accX = mfma_(al, w0h[kk], mfma_(ah, w0l[kk], mfma_(ah, w0h[kk], accX)));
        bf16x8 hh = *(const bf16x8*)(&Hmhi[l15 * 136 + koff]);
        bf16x8 hl = *(const bf16x8*)(&Hmlo[l15 * 136 + koff]);
        accH = mfma_(hl, w1h[kk], mfma_(hh, w1l[kk], mfma_(hh, w1h[kk], accH)));
      }
    }

    if (t > 0) {
      const int par = (t + 1) & 1;   // parity of the H[t-1] slice

      // ===== direct convergence: poll the 100 same-u producers, then this
      // WG invalidates its XCD's stale clean L2 lines (acquire-agent fence
      // => buffer_inv; r4/r5-verified) and mixes from L2. No relay hop.
      if (tid < R_) poll1(&flags[((tid << 1) | u) * 32], t);
      __syncthreads();
      if (tid == 0) __builtin_amdgcn_fence(__ATOMIC_ACQUIRE, "agent");
      __syncthreads();

      // ===== mixing: msg[b,h] = sum_i C[i][r]*H_fp8[i][b,h], L2-served sc0 ==
      // thread -> (b_local = tid>>5, h0 = (tid&31)*4): 4 elems, f32 accum.
      // 13 groups of rows {12x8 + 1x4}, 3 groups (24 loads) in flight.
      const u8* Hs = Hb + (size_t)par * SLICE
                   + (size_t)(u*16 + (tid >> 5)) * H_ + (tid & 31) * 4;
      f32x2 macc01 = {0.f, 0.f}, macc23 = {0.f, 0.f};
      int bufA[8], bufB[8], bufC[8];
      const u8* pI = Hs;
      ISSUE8(bufA, pI); pI += (size_t)8 * ROWB;
      ISSUE8(bufB, pI); pI += (size_t)8 * ROWB;
      ISSUE8(bufC, pI); pI += (size_t)8 * ROWB;
      int ci = 0;
      for (int it = 0; it < 3; ++it) {
        WAITV(16); PROC8(bufA, ci); ci += 8; ISSUE8(bufA, pI); pI += (size_t)8 * ROWB;
        WAITV(16); PROC8(bufB, ci); ci += 8; ISSUE8(bufB, pI); pI += (size_t)8 * ROWB;
        WAITV(16); PROC8(bufC, ci); ci += 8; ISSUE8(bufC, pI); pI += (size_t)8 * ROWB;
      }
      WAITV(16); PROC8(bufA, 72); ISSUE4(bufA, pI);   // pI == Hs + 96*ROWB
      WAITV(12); PROC8(bufB, 80);
      WAITV(4);  PROC8(bufC, 88);
      WAITV(0);  PROC4(bufA, 96);

      union { u16 h[4]; unsigned long long v; } mw;
      mw.h[0]=f2h(macc01[0]); mw.h[1]=f2h(macc01[1]);
      mw.h[2]=f2h(macc23[0]); mw.h[3]=f2h(macc23[1]);
      *(unsigned long long*)&msgS[(tid >> 5) * 136 + (tid & 31) * 4] = mw.v;
      __syncthreads();   // msgS ready; also guards Hm overwrite below

      // ===== seg2: msg @ Wrhh (A = f16 msg from LDS, B = register-resident) =
      #pragma unroll
      for (int kk = 0; kk < 4; ++kk) {
        int koff = kk * 32 + quad * 8;
        f16x8 a0 = *(const f16x8*)(&msgS[l15 * 136 + koff]);
        accX = mfma_h(a0, w2l[kk], mfma_h(a0, w2h[kk], accX));
      }
    } else {
      __syncthreads();   // guard Hm overwrite (seg1 reads done in all waves)
    }

    // ===== epilogue: tanh -> Hm (split bf16) + mS (f16 staging) =====
    {
      #pragma unroll
      for (int rr = 0; rr < 4; ++rr) {
        int br = quad*4 + rr;
        u16 h, l;
        float v = fast_tanh(accX[rr] + accH[rr] + bs);
        split2(v, h, l);
        Hmhi[br*136 + col] = h; Hmlo[br*136 + col] = l;
        mS[br*128 + col] = f2h(v);
      }
    }
    __syncthreads();   // Hm + mS ready

    // H transport: wave 0 (64 threads), one 32B chunk each (2x dwordx4 sc1);
    // flag posts right after wave-0's own vmcnt(0) — no extra barrier.
    if (tid < 64) {
      int row = tid >> 2, c = (tid & 3) * 32;
      u8* Hn = Hb + (size_t)(t & 1) * SLICE + (size_t)r * ROWB
             + (size_t)(u*16 + row) * H_ + c;
      const u16* p = &mS[row * 128 + c];
      st16_sc(Hn,      pack16(p));
      st16_sc(Hn + 16, pack16(p + 16));
      wait_vm();
      if (tid == 0) post_flag(&flags[w * 32 + 0], t + 1);
    }

    // ===== out-projection on waves 4..7 (parallel with wave-0 transport) ====
    {
      if (wv >= 4) {
        const int o = (wv - 4) * 16 + l15;
        f32x4 y0 = {0,0,0,0};
        #pragma unroll
        for (int kk = 0; kk < 4; ++kk) {
          int koff = kk * 32 + quad * 8;
          bf16x8 ah = *(const bf16x8*)(&Hmhi[l15 * 136 + koff]);
          bf16x8 al = *(const bf16x8*)(&Hmlo[l15 * 136 + koff]);
          y0 = mfma_(al, boh[kk], mfma_(ah, bol[kk], mfma_(ah, boh[kk], y0)));
        }
        if (bigpart) {
          u16* pp = part2 + ((size_t)t * R_ + r) * (B_*O_);
          #pragma unroll
          for (int rr = 0; rr < 4; ++rr)
            pp[(u*16 + quad*4 + rr)*O_ + o] = f2b(y0[rr]);   // plain cached stores
        } else {
          float* pp = part + (size_t)(t & 1) * (NWG2 * PB) + (size_t)w * PB;
          #pragma unroll
          for (int rr = 0; rr < 4; ++rr)
            astf(pp + (quad*4 + rr)*O_ + o, y0[rr]);
        }
      }
      if (!bigpart) {
        __syncthreads();
        if (tid == 0) post_flag(&flags[w * 32 + 1], t + 1);
      }
    }
  }
}

// big mode: out[t] = sum_r part2[t][r] + b_out  (dispatch boundary = coherence)
__global__ void __launch_bounds__(256)
reduce_out(const u16* __restrict__ part2, const float* __restrict__ boutf,
           float* __restrict__ out)
{
  const int t = blockIdx.x, tid = threadIdx.x;
  const u16* base = part2 + (size_t)t * R_ * (B_*O_) + tid * 8;
  float acc[8] = {0,0,0,0,0,0,0,0};
  for (int r2 = 0; r2 < R_; ++r2) {
    bf16x8 v = *(const bf16x8*)(base + (size_t)r2 * (B_*O_));
    #pragma unroll
    for (int j = 0; j < 8; ++j) acc[j] += b2f((u16)v[j]);
  }
  int e = tid * 8;
  #pragma unroll
  for (int j = 0; j < 8; ++j)
    out[(size_t)t * (B_*O_) + e + j] = acc[j] + boutf[(e + j) & (O_-1)];
}

extern "C" void kernel_launch(void* const* d_in, const int* in_sizes, int n_in,
                              void* d_out, int out_size, void* d_ws, size_t ws_size,
                              hipStream_t stream) {
  const void* xp    = d_in[0];
  const void* Cp    = d_in[1];
  const void* Wih   = d_in[2];
  const void* Whh   = d_in[3];
  const void* Wrhh  = d_in[4];
  const void* biasp = d_in[5];
  const void* Wout  = d_in[6];
  const void* boutp = d_in[7];
  float* outp = (float*)d_out;

  char* ws = (char*)d_ws;
  size_t off = 0;
  auto carve = [&](size_t bytes) -> void* {
    void* p = ws + off;
    off += (bytes + 255) & ~(size_t)255;
    return p;
  };
  u16*   xb    = (u16*)carve((size_t)2 * XOFF * 2);
  u8*    Hb    = (u8*)carve((size_t)2 * SLICE);                // fp8, 2 slices
  u16*   wihT  = (u16*)carve((size_t)2 * WOFF * 2);
  u16*   whhT  = (u16*)carve((size_t)2 * WOFF * 2);
  u16*   wrhhT = (u16*)carve((size_t)2 * WOFF * 2);            // split f16
  u16*   woutT = (u16*)carve((size_t)2 * OOFF * 2);
  float* cfp   = (float*)carve((size_t)R_ * R_ * 4);           // plain f32 C
  float* biasf = (float*)carve((size_t)R_ * H_ * 4);
  float* boutf = (float*)carve((size_t)O_ * 4);
  float* partp = (float*)carve((size_t)2 * NWG2 * PB * 4);     // small-mode
  int*   flagp = (int*)carve((size_t)256 * 32 * 4);
  int*   modep = (int*)carve(256);
  size_t part2_bytes = (size_t)T_ * R_ * B_ * O_ * 2;          // 52.4 MB
  u16*   part2 = (u16*)(ws + off);
  int bigpart = (off + part2_bytes) <= ws_size;

  hipMemsetAsync(flagp, 0, (size_t)256 * 32 * 4, stream);

  probe_dtype<<<dim3(1), dim3(256), 0, stream>>>((const u16*)xp, modep);
  conv_split<<<dim3((XOFF + 255)/256), dim3(256), 0, stream>>>(xp, xb, xb + XOFF, modep, XOFF);
  conv_vec<<<dim3((R_*H_ + 255)/256), dim3(256), 0, stream>>>(biasp, biasf, modep, R_*H_);
  conv_vec<<<dim3(1), dim3(256), 0, stream>>>(boutp, boutf, modep, O_);
  conv_vec<<<dim3((R_*R_ + 255)/256), dim3(256), 0, stream>>>(Cp, cfp, modep, R_*R_);

  transpose_kn2<<<dim3(R_ * 16), dim3(256), 0, stream>>>(Wih,  wihT,  wihT  + WOFF, I_, H_, modep, 0);
  transpose_kn2<<<dim3(R_ * 16), dim3(256), 0, stream>>>(Whh,  whhT,  whhT  + WOFF, H_, H_, modep, 0);
  transpose_kn2<<<dim3(R_ * 16), dim3(256), 0, stream>>>(Wrhh, wrhhT, wrhhT + WOFF, H_, H_, modep, 1);
  transpose_kn2<<<dim3(800),     dim3(256), 0, stream>>>(Wout, woutT, woutT + OOFF, R_ * H_, O_, modep, 0);

  // 200 (region, batch-half) WGs x 512 threads; +4 reducers in small mode
  int nblk = bigpart ? NWG2 : (NWG2 + NRED);
  rnn_kernel<<<dim3(nblk), dim3(512), 0, stream>>>(
      xb, Hb, wihT, whhT, wrhhT, cfp, biasf, woutT,
      partp, part2, boutf, outp, flagp, bigpart);

  if (bigpart)
    reduce_out<<<dim3(T_), dim3(256), 0, stream>>>(part2, boutf, outp);
}

// Round 7
// 1070.729 us; speedup vs baseline: 1.0380x; 1.0380x over previous
//
#include <hip/hip_runtime.h>
#include <hip/hip_bf16.h>

typedef unsigned char u8;
typedef unsigned short u16;
typedef __attribute__((ext_vector_type(8))) short bf16x8;
typedef __attribute__((ext_vector_type(8))) _Float16 f16x8;
typedef __attribute__((ext_vector_type(4))) float f32x4;
typedef __attribute__((ext_vector_type(2))) float f32x2;
typedef __attribute__((ext_vector_type(4))) int i32x4;
typedef __attribute__((ext_vector_type(2))) int i32x2;

#define T_ 128
#define B_ 32
#define I_ 128
#define H_ 128
#define R_ 100
#define O_ 64
#define NWG2 200              /* (region, batch-half) workgroups */
#define NRED 4                /* dedicated reducer WGs (small mode only) */
#define SLICE (R_*B_*H_)      /* bytes per fp8 H slice */
#define ROWB  (B_*H_)         /* 4096 bytes per region row in a slice */
#define XOFF  (T_*B_*I_)
#define WOFF  (R_*H_*H_)
#define OOFF  (O_*R_*H_)
#define PB    (16*O_)         /* small-mode part floats per WG slot */
#define SFBASE 6400           /* int offset of inv-flags inside flags[] */
#define XCNTOFF 7168          /* int offset of per-XCD WG counters */

__device__ __forceinline__ float b2f(u16 u) {
  unsigned x = ((unsigned)u) << 16; float f; __builtin_memcpy(&f, &x, 4); return f;
}
__device__ __forceinline__ u16 f2b(float f) {
  unsigned x; __builtin_memcpy(&x, &f, 4);
  unsigned lsb = (x >> 16) & 1u;
  x += 0x7fffu + lsb;
  return (u16)(x >> 16);
}
__device__ __forceinline__ void split2(float f, u16& hi, u16& lo) {
  hi = f2b(f);
  lo = f2b(f - b2f(hi));
}
__device__ __forceinline__ u16 f2h(float f) {
  _Float16 h = (_Float16)f; u16 u; __builtin_memcpy(&u, &h, 2); return u;
}
__device__ __forceinline__ float h2f(u16 u) {
  _Float16 h; __builtin_memcpy(&h, &u, 2); return (float)h;
}
__device__ __forceinline__ void split2h(float f, u16& hi, u16& lo) {
  _Float16 h = (_Float16)f;
  _Float16 l = (_Float16)(f - (float)h);
  __builtin_memcpy(&hi, &h, 2); __builtin_memcpy(&lo, &l, 2);
}
__device__ __forceinline__ float fast_tanh(float v) {
  float a = fabsf(v);
  float e = __expf(-2.f * a);
  float th = (1.f - e) * __builtin_amdgcn_rcpf(1.f + e);
  return v < 0.f ? -th : th;
}

// ---------------- fp8 e4m3 pack/unpack (HW builtin or bit-exact manual) ------
#if __has_builtin(__builtin_amdgcn_cvt_pk_f32_fp8) && __has_builtin(__builtin_amdgcn_cvt_pk_fp8_f32)
#define HW_FP8 1
#endif

__device__ __forceinline__ unsigned enc1_fp8(float f) {
  unsigned x; __builtin_memcpy(&x, &f, 4);
  unsigned s = (x >> 31) << 7;
  float a = fabsf(f);
  if (!(a < 464.f)) return s | 0x7E;
  if (a == 0.f) return s;
  int E = (int)((x >> 23) & 0xFF) - 127;
  if (E < -6) E = -6;
  float sc; unsigned sb = (unsigned)(127 + 3 - E) << 23; __builtin_memcpy(&sc, &sb, 4);
  int q = (int)rintf(a * sc);
  if (q == 16) { E += 1; q = 8; }
  if (E > 8) return s | 0x7E;
  unsigned ee, mm;
  if (q < 8) { ee = 0; mm = (unsigned)q; }
  else { ee = (unsigned)(E + 7); mm = (unsigned)(q - 8); }
  return s | (ee << 3) | mm;
}
__device__ __forceinline__ float dec1_fp8(unsigned b) {
  unsigned s = (b >> 7) & 1, ee = (b >> 3) & 0xF, mm = b & 7;
  float v;
  if (ee == 0) v = (float)mm * 0.001953125f;
  else { unsigned fb = ((ee + 120) << 23) | (mm << 20); __builtin_memcpy(&v, &fb, 4); }
  return s ? -v : v;
}
// decode 4 fp8 -> two f32 pairs
__device__ __forceinline__ void fp8x4_to_2x2(unsigned u, f32x2& a, f32x2& b) {
#ifdef HW_FP8
  a = __builtin_amdgcn_cvt_pk_f32_fp8((int)u, false);
  b = __builtin_amdgcn_cvt_pk_f32_fp8((int)u, true);
#else
  a[0] = dec1_fp8(u & 255); a[1] = dec1_fp8((u >> 8) & 255);
  b[0] = dec1_fp8((u >> 16) & 255); b[1] = dec1_fp8(u >> 24);
#endif
}
__device__ __forceinline__ void fp8x4_to_f32(unsigned u, float* o) {
  f32x2 a, b; fp8x4_to_2x2(u, a, b);
  o[0] = a[0]; o[1] = a[1]; o[2] = b[0]; o[3] = b[1];
}
__device__ __forceinline__ unsigned f32x4_to_fp8(float f0, float f1, float f2, float f3) {
#ifdef HW_FP8
  int v = __builtin_amdgcn_cvt_pk_fp8_f32(f0, f1, 0, false);
  v = __builtin_amdgcn_cvt_pk_fp8_f32(f2, f3, v, true);
  return (unsigned)v;
#else
  return enc1_fp8(f0) | (enc1_fp8(f1) << 8) | (enc1_fp8(f2) << 16) | (enc1_fp8(f3) << 24);
#endif
}
// pack 16 f16 (from LDS) -> 16 fp8 as i32x4
__device__ __forceinline__ i32x4 pack16(const u16* p) {
  i32x4 o;
  #pragma unroll
  for (int g = 0; g < 4; ++g)
    o[g] = (int)f32x4_to_fp8(h2f(p[g*4+0]), h2f(p[g*4+1]), h2f(p[g*4+2]), h2f(p[g*4+3]));
  return o;
}

// packed dual-f32 FMA (CDNA VOP3P): bit-exact per element vs v_fma_f32.
__device__ __forceinline__ f32x2 pk_fma(f32x2 a, f32x2 b, f32x2 c) {
  f32x2 d;
  asm("v_pk_fma_f32 %0, %1, %2, %3" : "=v"(d) : "v"(a), "v"(b), "v"(c));
  return d;
}

// ---- cache-scope accessors --------------------------------------------------
// sc1 store = agent scope (writes land at LLC).
// sc0 load  = bypass L1, served by local L2 (valid under the once-per-XCD
//             rank0 buffer_inv handshake — r5-verified; per-WG inv churns, r6).
__device__ __forceinline__ void st16_sc(void* p, i32x4 v) {
  asm volatile("global_store_dwordx4 %0, %1, off sc1" :: "v"(p), "v"(v) : "memory");
}
// issue-only 8B L2-cached load: NO waitcnt — caller manages vmcnt manually.
__device__ __forceinline__ void ld8_issue0(i32x2& r, const void* p) {
  asm volatile("global_load_dwordx2 %0, %1, off sc0" : "=v"(r) : "v"(p));
}
__device__ __forceinline__ void wait_vm() { asm volatile("s_waitcnt vmcnt(0)" ::: "memory"); }
// manual vmcnt wait + scheduling fence (guide rule #18)
#define WAITV(N) do { asm volatile("s_waitcnt vmcnt(" #N ")" ::: "memory"); \
                      __builtin_amdgcn_sched_barrier(0); } while (0)

__device__ __forceinline__ float aldf(const float* p) {
  return __hip_atomic_load((float*)p, __ATOMIC_RELAXED, __HIP_MEMORY_SCOPE_AGENT);
}
__device__ __forceinline__ void astf(float* p, float v) {
  __hip_atomic_store(p, v, __ATOMIC_RELAXED, __HIP_MEMORY_SCOPE_AGENT);
}

// ---- dtype probe ----
__global__ void __launch_bounds__(256)
probe_dtype(const u16* __restrict__ x, int* __restrict__ mode)
{
  __shared__ int cnt;
  if (threadIdx.x == 0) cnt = 0;
  __syncthreads();
  int bad = 0;
  for (int i = threadIdx.x; i < 8192; i += 256) {
    int ex = (x[i] >> 7) & 0xFF;
    if (ex >= 134) ++bad;
  }
  atomicAdd(&cnt, bad);
  __syncthreads();
  if (threadIdx.x == 0) *mode = (cnt > 256) ? 1 : 0;
}

__device__ __forceinline__ float load_in(const void* p, size_t i, int f32) {
  return f32 ? ((const float*)p)[i] : b2f(((const u16*)p)[i]);
}

__global__ void __launch_bounds__(256)
conv_split(const void* __restrict__ src, u16* __restrict__ hi, u16* __restrict__ lo,
           const int* __restrict__ mode, int n)
{
  int i = blockIdx.x * 256 + threadIdx.x;
  if (i < n) { u16 h, l; split2(load_in(src, i, *mode), h, l); hi[i] = h; lo[i] = l; }
}

__global__ void __launch_bounds__(256)
conv_vec(const void* __restrict__ src, float* __restrict__ dst,
         const int* __restrict__ mode, int n)
{
  int i = blockIdx.x * 256 + threadIdx.x;
  if (i < n) dst[i] = load_in(src, i, *mode);
}

// Tiled transpose -> split pair; fmt: 0 = bf16 split, 1 = f16 split
__global__ void __launch_bounds__(256)
transpose_kn2(const void* __restrict__ in, u16* __restrict__ ohi, u16* __restrict__ olo,
              int KK, int NN, const int* __restrict__ mode, int fmt)
{
  __shared__ float tile[32][33];
  const int f32 = *mode;
  int ntk = KK >> 5, ntn = NN >> 5;
  int bid = blockIdx.x;
  int m  = bid / (ntk * ntn);
  int rem = bid % (ntk * ntn);
  int kt = rem / ntn, nt = rem % ntn;
  size_t base = (size_t)m * KK * NN;
  int tid = threadIdx.x;
  int tc = tid & 31, tr0 = tid >> 5;
  #pragma unroll
  for (int rr = 0; rr < 4; ++rr) {
    int tr = tr0 + rr * 8;
    tile[tr][tc] = load_in(in, base + (size_t)(kt*32 + tr) * NN + nt*32 + tc, f32);
  }
  __syncthreads();
  #pragma unroll
  for (int rr = 0; rr < 4; ++rr) {
    int tr = tr0 + rr * 8;
    u16 h, l;
    if (fmt) split2h(tile[tc][tr], h, l); else split2(tile[tc][tr], h, l);
    size_t di = base + (size_t)(nt*32 + tr) * KK + kt*32 + tc;
    ohi[di] = h; olo[di] = l;
  }
}

// Full-barrier wait (small-mode reducer path)
__device__ __forceinline__ void wait_flags(const int* f, int cnt, int target, int tid) {
  if (tid < cnt) {
    int sp = 0;
    while (__hip_atomic_load((int*)&f[tid * 32], __ATOMIC_RELAXED, __HIP_MEMORY_SCOPE_AGENT) < target) {
      __builtin_amdgcn_s_sleep(2);
      if (++sp > (1 << 18)) break;
    }
  }
  asm volatile("" ::: "memory");
  __syncthreads();
}
// Per-thread poll: short hot spin, then backoff
__device__ __forceinline__ void poll1(const int* f, int target) {
  int sp = 0;
  while (__hip_atomic_load((int*)f, __ATOMIC_RELAXED, __HIP_MEMORY_SCOPE_AGENT) < target) {
    if (++sp > 48) __builtin_amdgcn_s_sleep(2);
    if (sp > (1 << 20)) break;
  }
  asm volatile("" ::: "memory");
}
__device__ __forceinline__ void post_flag(int* f, int v) {
  __hip_atomic_store(f, v, __ATOMIC_RELAXED, __HIP_MEMORY_SCOPE_AGENT);
}

__device__ __forceinline__ f32x4 mfma_(bf16x8 a, bf16x8 b, f32x4 c) {
  return __builtin_amdgcn_mfma_f32_16x16x32_bf16(a, b, c, 0, 0, 0);
}
__device__ __forceinline__ f32x4 mfma_h(f16x8 a, f16x8 b, f32x4 c) {
  return __builtin_amdgcn_mfma_f32_16x16x32_f16(a, b, c, 0, 0, 0);
}

// region-pair mixing: 8 elems (dwordx2 of fp8) scaled by csh2[2*CI+half]
#define MIXROW2(Q, CI) do { \
  f32x2 c2_ = csh2[((CI) << 1) + half]; \
  f32x2 a0_, a1_, b0_, b1_; \
  fp8x4_to_2x2((unsigned)(Q)[0], a0_, a1_); \
  fp8x4_to_2x2((unsigned)(Q)[1], b0_, b1_); \
  macc0 = pk_fma(a0_, c2_, macc0); macc1 = pk_fma(a1_, c2_, macc1); \
  macc2 = pk_fma(b0_, c2_, macc2); macc3 = pk_fma(b1_, c2_, macc3); \
} while (0)

#define ISSUE8P(Q, P) do { _Pragma("unroll") \
  for (int k_ = 0; k_ < 8; ++k_) ld8_issue0(Q[k_], (P) + (size_t)k_ * (2*ROWB)); } while (0)
#define ISSUE2P(Q, P) do { _Pragma("unroll") \
  for (int k_ = 0; k_ < 2; ++k_) ld8_issue0(Q[k_], (P) + (size_t)k_ * (2*ROWB)); } while (0)
#define PROC8P(Q, CI) do { _Pragma("unroll") \
  for (int k_ = 0; k_ < 8; ++k_) MIXROW2(Q[k_], (CI) + k_); } while (0)
#define PROC2P(Q, CI) do { _Pragma("unroll") \
  for (int k_ = 0; k_ < 2; ++k_) MIXROW2(Q[k_], (CI) + k_); } while (0)

// Single-hop persistent RNN; weights register-resident; mixing reads H from
// the local XCD L2 (sc0) after a once-per-XCD rank0 buffer_inv relay (r5).
// flags: [w*32] = H-ready gen, [w*32+1] = part-ready (small mode),
//        [(SFBASE + ((xcd<<1)+par)*32)] = inv-done gen,
//        [XCNTOFF + xcd] = per-XCD registration counter.
__global__ void __launch_bounds__(512, 2)
rnn_kernel(const u16* __restrict__ x,            // split bf16
           u8* __restrict__ Hb,                  // fp8, 2 slices (agent-coherent)
           const u16* __restrict__ WihT, const u16* __restrict__ WhhT,  // split bf16
           const u16* __restrict__ WrhhT,        // split f16
           const float* __restrict__ Cf,         // plain f32 C [R][R]
           const float* __restrict__ biasf,
           const u16* __restrict__ WoutT,        // split bf16
           float* __restrict__ part,             // small mode: 2-buf fp32
           u16* __restrict__ part2,              // big mode: [t][r] bf16 plain
           const float* __restrict__ boutf,
           float* __restrict__ out, int* __restrict__ flags, int bigpart)
{
  const int w    = blockIdx.x;
  const int tid  = threadIdx.x;
  const int lane = tid & 63;
  const int wv   = tid >> 6;          // 0..7
  const int l15  = lane & 15;
  const int quad = lane >> 4;

  __shared__ __align__(16) u16 Hmhi[16 * 136];   // local H state, split bf16
  __shared__ __align__(16) u16 Hmlo[16 * 136];
  __shared__ __align__(16) u16 msgS[16 * 136];   // mixed message, f16
  __shared__ __align__(16) u16 mS[16 * 128];     // H staging f16 for fp8 pack
  __shared__ __align__(16) f32x2 csh2[112];      // {C,C} pairs for this region
  __shared__ __align__(16) f32x2 redS[256][4];   // odd-half mixing partials
  __shared__ int shRank;

  // ---- dedicated reducer WGs (small mode only; grid = 204 then) ----
  if (w >= NWG2) {
    const int aw = w - NWG2;                     // 0..3
    for (int t = 0; t < T_; ++t) {
      wait_flags(flags + 1, NWG2, t + 1, tid);
      const float* pb = part + (size_t)(t & 1) * (NWG2 * PB);
      int e = aw * 512 + tid;                    // 0..2047
      int b = e >> 6, o = e & 63;
      int ue = b >> 4, bl = b & 15;
      float s = 0.f;
      #pragma unroll 4
      for (int r2 = 0; r2 < R_; ++r2)
        s += aldf(pb + (size_t)(r2 * 2 + ue) * PB + bl * O_ + o);
      out[(size_t)t * (B_*O_) + e] = s + boutf[o];
    }
    return;
  }

  // ---- XCD self-identification + rank election (workers only) ----
  int xcd;
  asm volatile("s_getreg_b32 %0, hwreg(HW_REG_XCC_ID)" : "=s"(xcd));
  xcd &= 7;
  if (tid == 0)
    shRank = __hip_atomic_fetch_add(&flags[XCNTOFF + xcd], 1,
                                    __ATOMIC_RELAXED, __HIP_MEMORY_SCOPE_AGENT);

  const int r = w >> 1;        // region
  const int u = w & 1;         // batch half (rows u*16 .. u*16+15)
  const int col = wv * 16 + l15;   // this thread's N column (0..127)

  for (int e = tid; e < 16 * 136; e += 512) { Hmhi[e] = 0; Hmlo[e] = 0; }
  if (tid < R_) {
    float c = Cf[(size_t)tid * R_ + r];
    f32x2 c2; c2[0] = c; c2[1] = c;
    csh2[tid] = c2;
  }
  __syncthreads();
  const int rank = shRank;

  // ---- hoist ALL t-invariant per-thread weight fragments into registers ----
  bf16x8 w0h[4], w0l[4], w1h[4], w1l[4];
  f16x8  w2h[4], w2l[4];
  bf16x8 boh[4], bol[4];
  {
    const u16* B0 = WihT  + (size_t)r * (H_*I_) + (size_t)col * 128;
    const u16* B1 = WhhT  + (size_t)r * (H_*H_) + (size_t)col * 128;
    const u16* B2 = WrhhT + (size_t)r * (H_*H_) + (size_t)col * 128;
    const int o = (wv >= 4) ? ((wv - 4) * 16 + l15) : l15;   // dummy for wv<4
    const u16* Bo = WoutT + (size_t)o * (R_*H_) + (size_t)r * H_;
    #pragma unroll
    for (int kk = 0; kk < 4; ++kk) {
      int koff = kk * 32 + quad * 8;
      w0h[kk] = *(const bf16x8*)(B0 + koff);
      w0l[kk] = *(const bf16x8*)(B0 + WOFF + koff);
      w1h[kk] = *(const bf16x8*)(B1 + koff);
      w1l[kk] = *(const bf16x8*)(B1 + WOFF + koff);
      w2h[kk] = *(const f16x8*)(B2 + koff);
      w2l[kk] = *(const f16x8*)(B2 + WOFF + koff);
      boh[kk] = *(const bf16x8*)(Bo + koff);
      bol[kk] = *(const bf16x8*)(Bo + OOFF + koff);
    }
  }
  const float bs = biasf[r*H_ + col];

  for (int t = 0; t < T_; ++t) {
    // ===== seg0 (x @ Wih) + seg1 (local H @ Whh), weights in regs =====
    f32x4 accX = {0,0,0,0}, accH = {0,0,0,0};
    {
      const u16* Ax = x + (size_t)t * (B_*I_) + (size_t)(u*16) * I_;
      #pragma unroll
      for (int kk = 0; kk < 4; ++kk) {
        int koff = kk * 32 + quad * 8;
        const u16* pa = Ax + (size_t)l15 * 128 + koff;
        bf16x8 ah = *(const bf16x8*)pa, al = *(const bf16x8*)(pa + XOFF);
        accX = mfma_(al, w0h[kk], mfma_(ah, w0l[kk], mfma_(ah, w0h[kk], accX)));
        bf16x8 hh = *(const bf16x8*)(&Hmhi[l15 * 136 + koff]);
        bf16x8 hl = *(const bf16x8*)(&Hmlo[l15 * 136 + koff]);
        accH = mfma_(hl, w1h[kk], mfma_(hh, w1l[kk], mfma_(hh, w1h[kk], accH)));
      }
    }

    if (t > 0) {
      const int par = (t + 1) & 1;   // parity of the H[t-1] slice
      int* invf = &flags[SFBASE + ((xcd << 1) + par) * 32];

      // ===== rank0 relay: gather all 200 flags, ONE buffer_inv per XCD per
      // step (agent acquire), post inv-done; consumers poll that flag only.
      if (rank == 0) {
        if (tid < NWG2) poll1(&flags[tid * 32], t);
        __syncthreads();
        if (tid == 0) {
          __builtin_amdgcn_fence(__ATOMIC_ACQUIRE, "agent");
          wait_vm();
          post_flag(invf, t);
        }
        __syncthreads();
      } else {
        if (tid == 0) poll1(invf, t);
        __syncthreads();
      }

      // ===== mixing: msg[b,h] = sum_i C[i][r]*H_fp8[i][b,h], L2-served sc0 ==
      // region-pair split: half = tid>>8 handles regions i = 2k+half;
      // thread covers 8 elems (b = s>>4, h0 = (s&15)*8) via dwordx2 loads.
      // 50 row-pairs: 6x8 + 2, 3 groups (24 loads) in flight.
      const int half = tid >> 8;
      const int s    = tid & 255;
      const int bb   = s >> 4;
      const int h0   = (s & 15) * 8;
      const u8* Hs = Hb + (size_t)par * SLICE + (size_t)half * ROWB
                   + (size_t)(u*16 + bb) * H_ + h0;
      f32x2 macc0 = {0.f,0.f}, macc1 = {0.f,0.f}, macc2 = {0.f,0.f}, macc3 = {0.f,0.f};
      i32x2 bufA[8], bufB[8], bufC[8];
      const u8* pI = Hs;
      ISSUE8P(bufA, pI); pI += (size_t)16 * ROWB;
      ISSUE8P(bufB, pI); pI += (size_t)16 * ROWB;
      ISSUE8P(bufC, pI); pI += (size_t)16 * ROWB;
      WAITV(16); PROC8P(bufA, 0);  ISSUE8P(bufA, pI); pI += (size_t)16 * ROWB;
      WAITV(16); PROC8P(bufB, 8);  ISSUE8P(bufB, pI); pI += (size_t)16 * ROWB;
      WAITV(16); PROC8P(bufC, 16); ISSUE8P(bufC, pI); pI += (size_t)16 * ROWB;
      WAITV(16); PROC8P(bufA, 24); ISSUE2P(bufA, pI);   // pI == Hs + 96*ROWB
      WAITV(10); PROC8P(bufB, 32);
      WAITV(2);  PROC8P(bufC, 40);
      WAITV(0);  PROC2P(bufA, 48);

      // cross-half reduce (even partial + odd partial), then f16 msgS write
      if (half) {
        redS[s][0] = macc0; redS[s][1] = macc1;
        redS[s][2] = macc2; redS[s][3] = macc3;
      }
      __syncthreads();
      if (!half) {
        f32x2 r0 = redS[s][0], r1 = redS[s][1], r2 = redS[s][2], r3 = redS[s][3];
        union { u16 h[8]; i32x4 v; } mw;
        mw.h[0] = f2h(macc0[0] + r0[0]); mw.h[1] = f2h(macc0[1] + r0[1]);
        mw.h[2] = f2h(macc1[0] + r1[0]); mw.h[3] = f2h(macc1[1] + r1[1]);
        mw.h[4] = f2h(macc2[0] + r2[0]); mw.h[5] = f2h(macc2[1] + r2[1]);
        mw.h[6] = f2h(macc3[0] + r3[0]); mw.h[7] = f2h(macc3[1] + r3[1]);
        *(i32x4*)&msgS[bb * 136 + h0] = mw.v;
      }
      __syncthreads();   // msgS ready; also guards Hm overwrite below

      // ===== seg2: msg @ Wrhh (A = f16 msg from LDS, B = register-resident) =
      #pragma unroll
      for (int kk = 0; kk < 4; ++kk) {
        int koff = kk * 32 + quad * 8;
        f16x8 a0 = *(const f16x8*)(&msgS[l15 * 136 + koff]);
        accX = mfma_h(a0, w2l[kk], mfma_h(a0, w2h[kk], accX));
      }
    } else {
      __syncthreads();   // guard Hm overwrite (seg1 reads done in all waves)
    }

    // ===== epilogue: tanh -> Hm (split bf16) + mS (f16 staging) =====
    {
      #pragma unroll
      for (int rr = 0; rr < 4; ++rr) {
        int br = quad*4 + rr;
        u16 h, l;
        float v = fast_tanh(accX[rr] + accH[rr] + bs);
        split2(v, h, l);
        Hmhi[br*136 + col] = h; Hmlo[br*136 + col] = l;
        mS[br*128 + col] = f2h(v);
      }
    }
    __syncthreads();   // Hm + mS ready

    // H transport: wave 0 (64 threads), one 32B chunk each (2x dwordx4 sc1);
    // flag posts right after wave-0's own vmcnt(0) — no extra barrier.
    if (tid < 64) {
      int row = tid >> 2, c = (tid & 3) * 32;
      u8* Hn = Hb + (size_t)(t & 1) * SLICE + (size_t)r * ROWB
             + (size_t)(u*16 + row) * H_ + c;
      const u16* p = &mS[row * 128 + c];
      st16_sc(Hn,      pack16(p));
      st16_sc(Hn + 16, pack16(p + 16));
      wait_vm();
      if (tid == 0) post_flag(&flags[w * 32 + 0], t + 1);
    }

    // ===== out-projection on waves 4..7 (parallel with wave-0 transport) ====
    {
      if (wv >= 4) {
        const int o = (wv - 4) * 16 + l15;
        f32x4 y0 = {0,0,0,0};
        #pragma unroll
        for (int kk = 0; kk < 4; ++kk) {
          int koff = kk * 32 + quad * 8;
          bf16x8 ah = *(const bf16x8*)(&Hmhi[l15 * 136 + koff]);
          bf16x8 al = *(const bf16x8*)(&Hmlo[l15 * 136 + koff]);
          y0 = mfma_(al, boh[kk], mfma_(ah, bol[kk], mfma_(ah, boh[kk], y0)));
        }
        if (bigpart) {
          u16* pp = part2 + ((size_t)t * R_ + r) * (B_*O_);
          #pragma unroll
          for (int rr = 0; rr < 4; ++rr)
            pp[(u*16 + quad*4 + rr)*O_ + o] = f2b(y0[rr]);   // plain cached stores
        } else {
          float* pp = part + (size_t)(t & 1) * (NWG2 * PB) + (size_t)w * PB;
          #pragma unroll
          for (int rr = 0; rr < 4; ++rr)
            astf(pp + (quad*4 + rr)*O_ + o, y0[rr]);
        }
      }
      if (!bigpart) {
        __syncthreads();
        if (tid == 0) post_flag(&flags[w * 32 + 1], t + 1);
      }
    }
  }
}

// big mode: out[t] = sum_r part2[t][r] + b_out  (dispatch boundary = coherence)
__global__ void __launch_bounds__(256)
reduce_out(const u16* __restrict__ part2, const float* __restrict__ boutf,
           float* __restrict__ out)
{
  const int t = blockIdx.x, tid = threadIdx.x;
  const u16* base = part2 + (size_t)t * R_ * (B_*O_) + tid * 8;
  float acc[8] = {0,0,0,0,0,0,0,0};
  for (int r2 = 0; r2 < R_; ++r2) {
    bf16x8 v = *(const bf16x8*)(base + (size_t)r2 * (B_*O_));
    #pragma unroll
    for (int j = 0; j < 8; ++j) acc[j] += b2f((u16)v[j]);
  }
  int e = tid * 8;
  #pragma unroll
  for (int j = 0; j < 8; ++j)
    out[(size_t)t * (B_*O_) + e + j] = acc[j] + boutf[(e + j) & (O_-1)];
}

extern "C" void kernel_launch(void* const* d_in, const int* in_sizes, int n_in,
                              void* d_out, int out_size, void* d_ws, size_t ws_size,
                              hipStream_t stream) {
  const void* xp    = d_in[0];
  const void* Cp    = d_in[1];
  const void* Wih   = d_in[2];
  const void* Whh   = d_in[3];
  const void* Wrhh  = d_in[4];
  const void* biasp = d_in[5];
  const void* Wout  = d_in[6];
  const void* boutp = d_in[7];
  float* outp = (float*)d_out;

  char* ws = (char*)d_ws;
  size_t off = 0;
  auto carve = [&](size_t bytes) -> void* {
    void* p = ws + off;
    off += (bytes + 255) & ~(size_t)255;
    return p;
  };
  u16*   xb    = (u16*)carve((size_t)2 * XOFF * 2);
  u8*    Hb    = (u8*)carve((size_t)2 * SLICE);                // fp8, 2 slices
  u16*   wihT  = (u16*)carve((size_t)2 * WOFF * 2);
  u16*   whhT  = (u16*)carve((size_t)2 * WOFF * 2);
  u16*   wrhhT = (u16*)carve((size_t)2 * WOFF * 2);            // split f16
  u16*   woutT = (u16*)carve((size_t)2 * OOFF * 2);
  float* cfp   = (float*)carve((size_t)R_ * R_ * 4);           // plain f32 C
  float* biasf = (float*)carve((size_t)R_ * H_ * 4);
  float* boutf = (float*)carve((size_t)O_ * 4);
  float* partp = (float*)carve((size_t)2 * NWG2 * PB * 4);     // small-mode
  int*   flagp = (int*)carve((size_t)256 * 32 * 4);
  int*   modep = (int*)carve(256);
  size_t part2_bytes = (size_t)T_ * R_ * B_ * O_ * 2;          // 52.4 MB
  u16*   part2 = (u16*)(ws + off);
  int bigpart = (off + part2_bytes) <= ws_size;

  hipMemsetAsync(flagp, 0, (size_t)256 * 32 * 4, stream);

  probe_dtype<<<dim3(1), dim3(256), 0, stream>>>((const u16*)xp, modep);
  conv_split<<<dim3((XOFF + 255)/256), dim3(256), 0, stream>>>(xp, xb, xb + XOFF, modep, XOFF);
  conv_vec<<<dim3((R_*H_ + 255)/256), dim3(256), 0, stream>>>(biasp, biasf, modep, R_*H_);
  conv_vec<<<dim3(1), dim3(256), 0, stream>>>(boutp, boutf, modep, O_);
  conv_vec<<<dim3((R_*R_ + 255)/256), dim3(256), 0, stream>>>(Cp, cfp, modep, R_*R_);

  transpose_kn2<<<dim3(R_ * 16), dim3(256), 0, stream>>>(Wih,  wihT,  wihT  + WOFF, I_, H_, modep, 0);
  transpose_kn2<<<dim3(R_ * 16), dim3(256), 0, stream>>>(Whh,  whhT,  whhT  + WOFF, H_, H_, modep, 0);
  transpose_kn2<<<dim3(R_ * 16), dim3(256), 0, stream>>>(Wrhh, wrhhT, wrhhT + WOFF, H_, H_, modep, 1);
  transpose_kn2<<<dim3(800),     dim3(256), 0, stream>>>(Wout, woutT, woutT + OOFF, R_ * H_, O_, modep, 0);

  // 200 (region, batch-half) WGs x 512 threads; +4 reducers in small mode
  int nblk = bigpart ? NWG2 : (NWG2 + NRED);
  rnn_kernel<<<dim3(nblk), dim3(512), 0, stream>>>(
      xb, Hb, wihT, whhT, wrhhT, cfp, biasf, woutT,
      partp, part2, boutf, outp, flagp, bigpart);

  if (bigpart)
    reduce_out<<<dim3(T_), dim3(256), 0, stream>>>(part2, boutf, outp);
}

// Round 8
// 980.039 us; speedup vs baseline: 1.1340x; 1.0925x over previous
//
#include <hip/hip_runtime.h>
#include <hip/hip_bf16.h>

typedef unsigned char u8;
typedef unsigned short u16;
typedef __attribute__((ext_vector_type(8))) short bf16x8;
typedef __attribute__((ext_vector_type(8))) _Float16 f16x8;
typedef __attribute__((ext_vector_type(4))) float f32x4;
typedef __attribute__((ext_vector_type(2))) float f32x2;
typedef __attribute__((ext_vector_type(4))) int i32x4;

#define T_ 128
#define B_ 32
#define I_ 128
#define H_ 128
#define R_ 100
#define O_ 64
#define NWG2 200              /* (region, batch-half) workgroups */
#define NRED 4                /* dedicated reducer WGs (small mode only) */
#define SLICE (R_*B_*H_)      /* bytes per fp8 H slice */
#define ROWB  (B_*H_)         /* 4096 bytes per region row in a slice */
#define XOFF  (T_*B_*I_)
#define WOFF  (R_*H_*H_)
#define OOFF  (O_*R_*H_)
#define PB    (16*O_)         /* small-mode part floats per WG slot */
#define SFBASE 6400           /* int offset of inv-flags inside flags[] */
#define XCNTOFF 7168          /* int offset of per-XCD WG counters */

__device__ __forceinline__ float b2f(u16 u) {
  unsigned x = ((unsigned)u) << 16; float f; __builtin_memcpy(&f, &x, 4); return f;
}
__device__ __forceinline__ u16 f2b(float f) {
  unsigned x; __builtin_memcpy(&x, &f, 4);
  unsigned lsb = (x >> 16) & 1u;
  x += 0x7fffu + lsb;
  return (u16)(x >> 16);
}
__device__ __forceinline__ void split2(float f, u16& hi, u16& lo) {
  hi = f2b(f);
  lo = f2b(f - b2f(hi));
}
__device__ __forceinline__ u16 f2h(float f) {
  _Float16 h = (_Float16)f; u16 u; __builtin_memcpy(&u, &h, 2); return u;
}
__device__ __forceinline__ float h2f(u16 u) {
  _Float16 h; __builtin_memcpy(&h, &u, 2); return (float)h;
}
__device__ __forceinline__ void split2h(float f, u16& hi, u16& lo) {
  _Float16 h = (_Float16)f;
  _Float16 l = (_Float16)(f - (float)h);
  __builtin_memcpy(&hi, &h, 2); __builtin_memcpy(&lo, &l, 2);
}
__device__ __forceinline__ float fast_tanh(float v) {
  float a = fabsf(v);
  float e = __expf(-2.f * a);
  float th = (1.f - e) * __builtin_amdgcn_rcpf(1.f + e);
  return v < 0.f ? -th : th;
}

// ---------------- fp8 e4m3 pack/unpack (HW builtin or bit-exact manual) ------
#if __has_builtin(__builtin_amdgcn_cvt_pk_f32_fp8) && __has_builtin(__builtin_amdgcn_cvt_pk_fp8_f32)
#define HW_FP8 1
#endif

__device__ __forceinline__ unsigned enc1_fp8(float f) {
  unsigned x; __builtin_memcpy(&x, &f, 4);
  unsigned s = (x >> 31) << 7;
  float a = fabsf(f);
  if (!(a < 464.f)) return s | 0x7E;
  if (a == 0.f) return s;
  int E = (int)((x >> 23) & 0xFF) - 127;
  if (E < -6) E = -6;
  float sc; unsigned sb = (unsigned)(127 + 3 - E) << 23; __builtin_memcpy(&sc, &sb, 4);
  int q = (int)rintf(a * sc);
  if (q == 16) { E += 1; q = 8; }
  if (E > 8) return s | 0x7E;
  unsigned ee, mm;
  if (q < 8) { ee = 0; mm = (unsigned)q; }
  else { ee = (unsigned)(E + 7); mm = (unsigned)(q - 8); }
  return s | (ee << 3) | mm;
}
__device__ __forceinline__ float dec1_fp8(unsigned b) {
  unsigned s = (b >> 7) & 1, ee = (b >> 3) & 0xF, mm = b & 7;
  float v;
  if (ee == 0) v = (float)mm * 0.001953125f;
  else { unsigned fb = ((ee + 120) << 23) | (mm << 20); __builtin_memcpy(&v, &fb, 4); }
  return s ? -v : v;
}
// decode 4 fp8 -> two f32 pairs
__device__ __forceinline__ void fp8x4_to_2x2(unsigned u, f32x2& a, f32x2& b) {
#ifdef HW_FP8
  a = __builtin_amdgcn_cvt_pk_f32_fp8((int)u, false);
  b = __builtin_amdgcn_cvt_pk_f32_fp8((int)u, true);
#else
  a[0] = dec1_fp8(u & 255); a[1] = dec1_fp8((u >> 8) & 255);
  b[0] = dec1_fp8((u >> 16) & 255); b[1] = dec1_fp8(u >> 24);
#endif
}
__device__ __forceinline__ unsigned f32x4_to_fp8(float f0, float f1, float f2, float f3) {
#ifdef HW_FP8
  int v = __builtin_amdgcn_cvt_pk_fp8_f32(f0, f1, 0, false);
  v = __builtin_amdgcn_cvt_pk_fp8_f32(f2, f3, v, true);
  return (unsigned)v;
#else
  return enc1_fp8(f0) | (enc1_fp8(f1) << 8) | (enc1_fp8(f2) << 16) | (enc1_fp8(f3) << 24);
#endif
}
// pack 16 f16 (from LDS) -> 16 fp8 as i32x4
__device__ __forceinline__ i32x4 pack16(const u16* p) {
  i32x4 o;
  #pragma unroll
  for (int g = 0; g < 4; ++g)
    o[g] = (int)f32x4_to_fp8(h2f(p[g*4+0]), h2f(p[g*4+1]), h2f(p[g*4+2]), h2f(p[g*4+3]));
  return o;
}

// packed dual-f32 FMA (CDNA VOP3P): bit-exact per element vs v_fma_f32.
__device__ __forceinline__ f32x2 pk_fma(f32x2 a, f32x2 b, f32x2 c) {
  f32x2 d;
  asm("v_pk_fma_f32 %0, %1, %2, %3" : "=v"(d) : "v"(a), "v"(b), "v"(c));
  return d;
}

// ---- cache-scope accessors --------------------------------------------------
// sc1 store = agent scope (writes land at LLC).
// sc0 load  = bypass L1, served by local L2 (valid under once-per-XCD
//             buffer_inv ordered before consumers' reads — r5-verified).
__device__ __forceinline__ void st16_sc(void* p, i32x4 v) {
  asm volatile("global_store_dwordx4 %0, %1, off sc1" :: "v"(p), "v"(v) : "memory");
}
// issue-only 4B L2-cached load: NO waitcnt — caller manages vmcnt manually.
__device__ __forceinline__ void ld4_issue0(int& r, const void* p) {
  asm volatile("global_load_dword %0, %1, off sc0" : "=v"(r) : "v"(p));
}
__device__ __forceinline__ void wait_vm() { asm volatile("s_waitcnt vmcnt(0)" ::: "memory"); }
// manual vmcnt wait + scheduling fence (guide rule #18)
#define WAITV(N) do { asm volatile("s_waitcnt vmcnt(" #N ")" ::: "memory"); \
                      __builtin_amdgcn_sched_barrier(0); } while (0)

__device__ __forceinline__ float aldf(const float* p) {
  return __hip_atomic_load((float*)p, __ATOMIC_RELAXED, __HIP_MEMORY_SCOPE_AGENT);
}
__device__ __forceinline__ void astf(float* p, float v) {
  __hip_atomic_store(p, v, __ATOMIC_RELAXED, __HIP_MEMORY_SCOPE_AGENT);
}

// ---- dtype probe ----
__global__ void __launch_bounds__(256)
probe_dtype(const u16* __restrict__ x, int* __restrict__ mode)
{
  __shared__ int cnt;
  if (threadIdx.x == 0) cnt = 0;
  __syncthreads();
  int bad = 0;
  for (int i = threadIdx.x; i < 8192; i += 256) {
    int ex = (x[i] >> 7) & 0xFF;
    if (ex >= 134) ++bad;
  }
  atomicAdd(&cnt, bad);
  __syncthreads();
  if (threadIdx.x == 0) *mode = (cnt > 256) ? 1 : 0;
}

__device__ __forceinline__ float load_in(const void* p, size_t i, int f32) {
  return f32 ? ((const float*)p)[i] : b2f(((const u16*)p)[i]);
}

__global__ void __launch_bounds__(256)
conv_split(const void* __restrict__ src, u16* __restrict__ hi, u16* __restrict__ lo,
           const int* __restrict__ mode, int n)
{
  int i = blockIdx.x * 256 + threadIdx.x;
  if (i < n) { u16 h, l; split2(load_in(src, i, *mode), h, l); hi[i] = h; lo[i] = l; }
}

__global__ void __launch_bounds__(256)
conv_vec(const void* __restrict__ src, float* __restrict__ dst,
         const int* __restrict__ mode, int n)
{
  int i = blockIdx.x * 256 + threadIdx.x;
  if (i < n) dst[i] = load_in(src, i, *mode);
}

// Tiled transpose -> split pair; fmt: 0 = bf16 split, 1 = f16 split
__global__ void __launch_bounds__(256)
transpose_kn2(const void* __restrict__ in, u16* __restrict__ ohi, u16* __restrict__ olo,
              int KK, int NN, const int* __restrict__ mode, int fmt)
{
  __shared__ float tile[32][33];
  const int f32 = *mode;
  int ntk = KK >> 5, ntn = NN >> 5;
  int bid = blockIdx.x;
  int m  = bid / (ntk * ntn);
  int rem = bid % (ntk * ntn);
  int kt = rem / ntn, nt = rem % ntn;
  size_t base = (size_t)m * KK * NN;
  int tid = threadIdx.x;
  int tc = tid & 31, tr0 = tid >> 5;
  #pragma unroll
  for (int rr = 0; rr < 4; ++rr) {
    int tr = tr0 + rr * 8;
    tile[tr][tc] = load_in(in, base + (size_t)(kt*32 + tr) * NN + nt*32 + tc, f32);
  }
  __syncthreads();
  #pragma unroll
  for (int rr = 0; rr < 4; ++rr) {
    int tr = tr0 + rr * 8;
    u16 h, l;
    if (fmt) split2h(tile[tc][tr], h, l); else split2(tile[tc][tr], h, l);
    size_t di = base + (size_t)(nt*32 + tr) * KK + kt*32 + tc;
    ohi[di] = h; olo[di] = l;
  }
}

// Full-barrier wait (small-mode reducer path)
__device__ __forceinline__ void wait_flags(const int* f, int cnt, int target, int tid) {
  if (tid < cnt) {
    int sp = 0;
    while (__hip_atomic_load((int*)&f[tid * 32], __ATOMIC_RELAXED, __HIP_MEMORY_SCOPE_AGENT) < target) {
      __builtin_amdgcn_s_sleep(2);
      if (++sp > (1 << 18)) break;
    }
  }
  asm volatile("" ::: "memory");
  __syncthreads();
}
// Per-thread poll: short hot spin, then backoff
__device__ __forceinline__ void poll1(const int* f, int target) {
  int sp = 0;
  while (__hip_atomic_load((int*)f, __ATOMIC_RELAXED, __HIP_MEMORY_SCOPE_AGENT) < target) {
    if (++sp > 48) __builtin_amdgcn_s_sleep(2);
    if (sp > (1 << 20)) break;
  }
  asm volatile("" ::: "memory");
}
__device__ __forceinline__ void post_flag(int* f, int v) {
  __hip_atomic_store(f, v, __ATOMIC_RELAXED, __HIP_MEMORY_SCOPE_AGENT);
}

__device__ __forceinline__ f32x4 mfma_(bf16x8 a, bf16x8 b, f32x4 c) {
  return __builtin_amdgcn_mfma_f32_16x16x32_bf16(a, b, c, 0, 0, 0);
}
__device__ __forceinline__ f32x4 mfma_h(f16x8 a, f16x8 b, f32x4 c) {
  return __builtin_amdgcn_mfma_f32_16x16x32_f16(a, b, c, 0, 0, 0);
}

// per-row mixing: macc01/macc23 += {C,C} * fp8x4(H row fragment)
// 5 issue slots/row: load + 2 cvt_pk + 2 v_pk_fma_f32
#define MIXROW(Q, CI) do { \
  f32x2 c2_ = csh2[(CI)]; \
  f32x2 a_, b_; fp8x4_to_2x2((unsigned)(Q), a_, b_); \
  macc01 = pk_fma(a_, c2_, macc01); \
  macc23 = pk_fma(b_, c2_, macc23); \
} while (0)

#define ISSUE8(Q, P) do { _Pragma("unroll") \
  for (int k_ = 0; k_ < 8; ++k_) ld4_issue0(Q[k_], (P) + (size_t)k_ * ROWB); } while (0)
#define ISSUE4(Q, P) do { _Pragma("unroll") \
  for (int k_ = 0; k_ < 4; ++k_) ld4_issue0(Q[k_], (P) + (size_t)k_ * ROWB); } while (0)
#define PROC8(Q, CI) do { _Pragma("unroll") \
  for (int k_ = 0; k_ < 8; ++k_) MIXROW(Q[k_], (CI) + k_); } while (0)
#define PROC4(Q, CI) do { _Pragma("unroll") \
  for (int k_ = 0; k_ < 4; ++k_) MIXROW(Q[k_], (CI) + k_); } while (0)

// Single-hop persistent RNN; weights register-resident; mixing reads H from
// the local XCD L2 (sc0). Invalidation is PIPELINED: each XCD's rank0 WG, at
// the END of its step t, (a) confirms all 200 WGs passed step t-1 (their gen-t
// flags — normally already set, off the critical path), (b) buffer_inv, and
// (c) posts invf[xcd] = t+1 "L2 clean for step t+1 consumers". Consumers poll
// only their 100 same-u producer flags + invf — one LLC hop after the last
// producer, vs three in the r5 relay. The (a) poll closes the laggard
// re-caching race: no step-(t-1) mixing read can land after this inv.
// flags: [w*32] = H-ready gen, [w*32+1] = part-ready (small mode),
//        [SFBASE + xcd*32] = inv-done gen, [XCNTOFF + xcd] = WG counter.
__global__ void __launch_bounds__(512, 2)
rnn_kernel(const u16* __restrict__ x,            // split bf16
           u8* __restrict__ Hb,                  // fp8, 2 slices (agent-coherent)
           const u16* __restrict__ WihT, const u16* __restrict__ WhhT,  // split bf16
           const u16* __restrict__ WrhhT,        // split f16
           const float* __restrict__ Cf,         // plain f32 C [R][R]
           const float* __restrict__ biasf,
           const u16* __restrict__ WoutT,        // split bf16
           float* __restrict__ part,             // small mode: 2-buf fp32
           u16* __restrict__ part2,              // big mode: [t][r] bf16 plain
           const float* __restrict__ boutf,
           float* __restrict__ out, int* __restrict__ flags, int bigpart)
{
  const int w    = blockIdx.x;
  const int tid  = threadIdx.x;
  const int lane = tid & 63;
  const int wv   = tid >> 6;          // 0..7
  const int l15  = lane & 15;
  const int quad = lane >> 4;

  __shared__ __align__(16) u16 Hmhi[16 * 136];   // local H state, split bf16
  __shared__ __align__(16) u16 Hmlo[16 * 136];
  __shared__ __align__(16) u16 msgS[16 * 136];   // mixed message, f16
  __shared__ __align__(16) u16 mS[16 * 128];     // H staging f16 for fp8 pack
  __shared__ __align__(16) f32x2 csh2[112];      // {C,C} pairs for this region
  __shared__ int shRank;

  // ---- dedicated reducer WGs (small mode only; grid = 204 then) ----
  if (w >= NWG2) {
    const int aw = w - NWG2;                     // 0..3
    for (int t = 0; t < T_; ++t) {
      wait_flags(flags + 1, NWG2, t + 1, tid);
      const float* pb = part + (size_t)(t & 1) * (NWG2 * PB);
      int e = aw * 512 + tid;                    // 0..2047
      int b = e >> 6, o = e & 63;
      int ue = b >> 4, bl = b & 15;
      float s = 0.f;
      #pragma unroll 4
      for (int r2 = 0; r2 < R_; ++r2)
        s += aldf(pb + (size_t)(r2 * 2 + ue) * PB + bl * O_ + o);
      out[(size_t)t * (B_*O_) + e] = s + boutf[o];
    }
    return;
  }

  // ---- XCD self-identification + rank election (workers only) ----
  int xcd;
  asm volatile("s_getreg_b32 %0, hwreg(HW_REG_XCC_ID)" : "=s"(xcd));
  xcd &= 7;
  if (tid == 0)
    shRank = __hip_atomic_fetch_add(&flags[XCNTOFF + xcd], 1,
                                    __ATOMIC_RELAXED, __HIP_MEMORY_SCOPE_AGENT);

  const int r = w >> 1;        // region
  const int u = w & 1;         // batch half (rows u*16 .. u*16+15)
  const int col = wv * 16 + l15;   // this thread's N column (0..127)
  int* invf = &flags[SFBASE + xcd * 32];

  for (int e = tid; e < 16 * 136; e += 512) { Hmhi[e] = 0; Hmlo[e] = 0; }
  if (tid < R_) {
    float c = Cf[(size_t)tid * R_ + r];
    f32x2 c2; c2[0] = c; c2[1] = c;
    csh2[tid] = c2;
  }
  __syncthreads();
  const int rank = shRank;

  // ---- hoist ALL t-invariant per-thread weight fragments into registers ----
  bf16x8 w0h[4], w0l[4], w1h[4], w1l[4];
  f16x8  w2h[4], w2l[4];
  bf16x8 boh[4], bol[4];
  {
    const u16* B0 = WihT  + (size_t)r * (H_*I_) + (size_t)col * 128;
    const u16* B1 = WhhT  + (size_t)r * (H_*H_) + (size_t)col * 128;
    const u16* B2 = WrhhT + (size_t)r * (H_*H_) + (size_t)col * 128;
    const int o = (wv >= 4) ? ((wv - 4) * 16 + l15) : l15;   // dummy for wv<4
    const u16* Bo = WoutT + (size_t)o * (R_*H_) + (size_t)r * H_;
    #pragma unroll
    for (int kk = 0; kk < 4; ++kk) {
      int koff = kk * 32 + quad * 8;
      w0h[kk] = *(const bf16x8*)(B0 + koff);
      w0l[kk] = *(const bf16x8*)(B0 + WOFF + koff);
      w1h[kk] = *(const bf16x8*)(B1 + koff);
      w1l[kk] = *(const bf16x8*)(B1 + WOFF + koff);
      w2h[kk] = *(const f16x8*)(B2 + koff);
      w2l[kk] = *(const f16x8*)(B2 + WOFF + koff);
      boh[kk] = *(const bf16x8*)(Bo + koff);
      bol[kk] = *(const bf16x8*)(Bo + OOFF + koff);
    }
  }
  const float bs = biasf[r*H_ + col];

  for (int t = 0; t < T_; ++t) {
    // ===== seg0 (x @ Wih) + seg1 (local H @ Whh), weights in regs =====
    f32x4 accX = {0,0,0,0}, accH = {0,0,0,0};
    {
      const u16* Ax = x + (size_t)t * (B_*I_) + (size_t)(u*16) * I_;
      #pragma unroll
      for (int kk = 0; kk < 4; ++kk) {
        int koff = kk * 32 + quad * 8;
        const u16* pa = Ax + (size_t)l15 * 128 + koff;
        bf16x8 ah = *(const bf16x8*)pa, al = *(const bf16x8*)(pa + XOFF);
        accX = mfma_(al, w0h[kk], mfma_(ah, w0l[kk], mfma_(ah, w0h[kk], accX)));
        bf16x8 hh = *(const bf16x8*)(&Hmhi[l15 * 136 + koff]);
        bf16x8 hl = *(const bf16x8*)(&Hmlo[l15 * 136 + koff]);
        accH = mfma_(hl, w1h[kk], mfma_(hh, w1l[kk], mfma_(hh, w1h[kk], accH)));
      }
    }

    if (t > 0) {
      const int par = (t + 1) & 1;   // parity of the H[t-1] slice

      // ===== direct convergence: 100 same-u producers + this XCD's inv flag.
      // invf >= t was posted at the end of rank0's step t-1 — normally long
      // before the last producer posts, so the binding wait is ONE hop.
      if (tid < R_) poll1(&flags[((tid << 1) | u) * 32], t);
      else if (tid == 128) poll1(invf, t);
      __syncthreads();

      // ===== mixing: msg[b,h] = sum_i C[i][r]*H_fp8[i][b,h], L2-served sc0 ==
      // thread -> (b_local = tid>>5, h0 = (tid&31)*4): 4 elems, f32 accum.
      // 13 groups of rows {12x8 + 1x4}, 3 groups (24 loads) in flight.
      const u8* Hs = Hb + (size_t)par * SLICE
                   + (size_t)(u*16 + (tid >> 5)) * H_ + (tid & 31) * 4;
      f32x2 macc01 = {0.f, 0.f}, macc23 = {0.f, 0.f};
      int bufA[8], bufB[8], bufC[8];
      const u8* pI = Hs;
      ISSUE8(bufA, pI); pI += (size_t)8 * ROWB;
      ISSUE8(bufB, pI); pI += (size_t)8 * ROWB;
      ISSUE8(bufC, pI); pI += (size_t)8 * ROWB;
      int ci = 0;
      for (int it = 0; it < 3; ++it) {
        WAITV(16); PROC8(bufA, ci); ci += 8; ISSUE8(bufA, pI); pI += (size_t)8 * ROWB;
        WAITV(16); PROC8(bufB, ci); ci += 8; ISSUE8(bufB, pI); pI += (size_t)8 * ROWB;
        WAITV(16); PROC8(bufC, ci); ci += 8; ISSUE8(bufC, pI); pI += (size_t)8 * ROWB;
      }
      WAITV(16); PROC8(bufA, 72); ISSUE4(bufA, pI);   // pI == Hs + 96*ROWB
      WAITV(12); PROC8(bufB, 80);
      WAITV(4);  PROC8(bufC, 88);
      WAITV(0);  PROC4(bufA, 96);

      union { u16 h[4]; unsigned long long v; } mw;
      mw.h[0]=f2h(macc01[0]); mw.h[1]=f2h(macc01[1]);
      mw.h[2]=f2h(macc23[0]); mw.h[3]=f2h(macc23[1]);
      *(unsigned long long*)&msgS[(tid >> 5) * 136 + (tid & 31) * 4] = mw.v;
      __syncthreads();   // msgS ready; also guards Hm overwrite below

      // ===== seg2: msg @ Wrhh (A = f16 msg from LDS, B = register-resident) =
      #pragma unroll
      for (int kk = 0; kk < 4; ++kk) {
        int koff = kk * 32 + quad * 8;
        f16x8 a0 = *(const f16x8*)(&msgS[l15 * 136 + koff]);
        accX = mfma_h(a0, w2l[kk], mfma_h(a0, w2h[kk], accX));
      }
    } else {
      __syncthreads();   // guard Hm overwrite (seg1 reads done in all waves)
    }

    // ===== epilogue: tanh -> Hm (split bf16) + mS (f16 staging) =====
    {
      #pragma unroll
      for (int rr = 0; rr < 4; ++rr) {
        int br = quad*4 + rr;
        u16 h, l;
        float v = fast_tanh(accX[rr] + accH[rr] + bs);
        split2(v, h, l);
        Hmhi[br*136 + col] = h; Hmlo[br*136 + col] = l;
        mS[br*128 + col] = f2h(v);
      }
    }
    __syncthreads();   // Hm + mS ready

    // H transport: wave 0 (64 threads), one 32B chunk each (2x dwordx4 sc1);
    // flag posts right after wave-0's own vmcnt(0) — no extra barrier.
    if (tid < 64) {
      int row = tid >> 2, c = (tid & 3) * 32;
      u8* Hn = Hb + (size_t)(t & 1) * SLICE + (size_t)r * ROWB
             + (size_t)(u*16 + row) * H_ + c;
      const u16* p = &mS[row * 128 + c];
      st16_sc(Hn,      pack16(p));
      st16_sc(Hn + 16, pack16(p + 16));
      wait_vm();
      if (tid == 0) post_flag(&flags[w * 32 + 0], t + 1);
    }

    // ===== rank0 pipelined invalidation (end of step t, covers step t+1) ====
    // (a) all 200 WGs passed step t-1 (gen-t flags; normally instant) so no
    //     step-(t-1) mixing read can re-cache after the inv; (b) buffer_inv;
    //     (c) post invf = t+1.
    if (rank == 0) {
      if (tid < NWG2) poll1(&flags[tid * 32], t);
      __syncthreads();
      if (tid == 0) {
        __builtin_amdgcn_fence(__ATOMIC_ACQUIRE, "agent");
        wait_vm();
        post_flag(invf, t + 1);
      }
    }

    // ===== out-projection on waves 4..7 (parallel with wave-0 transport) ====
    {
      if (wv >= 4) {
        const int o = (wv - 4) * 16 + l15;
        f32x4 y0 = {0,0,0,0};
        #pragma unroll
        for (int kk = 0; kk < 4; ++kk) {
          int koff = kk * 32 + quad * 8;
          bf16x8 ah = *(const bf16x8*)(&Hmhi[l15 * 136 + koff]);
          bf16x8 al = *(const bf16x8*)(&Hmlo[l15 * 136 + koff]);
          y0 = mfma_(al, boh[kk], mfma_(ah, bol[kk], mfma_(ah, boh[kk], y0)));
        }
        if (bigpart) {
          u16* pp = part2 + ((size_t)t * R_ + r) * (B_*O_);
          #pragma unroll
          for (int rr = 0; rr < 4; ++rr)
            pp[(u*16 + quad*4 + rr)*O_ + o] = f2b(y0[rr]);   // plain cached stores
        } else {
          float* pp = part + (size_t)(t & 1) * (NWG2 * PB) + (size_t)w * PB;
          #pragma unroll
          for (int rr = 0; rr < 4; ++rr)
            astf(pp + (quad*4 + rr)*O_ + o, y0[rr]);
        }
      }
      if (!bigpart) {
        __syncthreads();
        if (tid == 0) post_flag(&flags[w * 32 + 1], t + 1);
      }
    }
  }
}

// big mode: out[t] = sum_r part2[t][r] + b_out  (dispatch boundary = coherence)
__global__ void __launch_bounds__(256)
reduce_out(const u16* __restrict__ part2, const float* __restrict__ boutf,
           float* __restrict__ out)
{
  const int t = blockIdx.x, tid = threadIdx.x;
  const u16* base = part2 + (size_t)t * R_ * (B_*O_) + tid * 8;
  float acc[8] = {0,0,0,0,0,0,0,0};
  for (int r2 = 0; r2 < R_; ++r2) {
    bf16x8 v = *(const bf16x8*)(base + (size_t)r2 * (B_*O_));
    #pragma unroll
    for (int j = 0; j < 8; ++j) acc[j] += b2f((u16)v[j]);
  }
  int e = tid * 8;
  #pragma unroll
  for (int j = 0; j < 8; ++j)
    out[(size_t)t * (B_*O_) + e + j] = acc[j] + boutf[(e + j) & (O_-1)];
}

extern "C" void kernel_launch(void* const* d_in, const int* in_sizes, int n_in,
                              void* d_out, int out_size, void* d_ws, size_t ws_size,
                              hipStream_t stream) {
  const void* xp    = d_in[0];
  const void* Cp    = d_in[1];
  const void* Wih   = d_in[2];
  const void* Whh   = d_in[3];
  const void* Wrhh  = d_in[4];
  const void* biasp = d_in[5];
  const void* Wout  = d_in[6];
  const void* boutp = d_in[7];
  float* outp = (float*)d_out;

  char* ws = (char*)d_ws;
  size_t off = 0;
  auto carve = [&](size_t bytes) -> void* {
    void* p = ws + off;
    off += (bytes + 255) & ~(size_t)255;
    return p;
  };
  u16*   xb    = (u16*)carve((size_t)2 * XOFF * 2);
  u8*    Hb    = (u8*)carve((size_t)2 * SLICE);                // fp8, 2 slices
  u16*   wihT  = (u16*)carve((size_t)2 * WOFF * 2);
  u16*   whhT  = (u16*)carve((size_t)2 * WOFF * 2);
  u16*   wrhhT = (u16*)carve((size_t)2 * WOFF * 2);            // split f16
  u16*   woutT = (u16*)carve((size_t)2 * OOFF * 2);
  float* cfp   = (float*)carve((size_t)R_ * R_ * 4);           // plain f32 C
  float* biasf = (float*)carve((size_t)R_ * H_ * 4);
  float* boutf = (float*)carve((size_t)O_ * 4);
  float* partp = (float*)carve((size_t)2 * NWG2 * PB * 4);     // small-mode
  int*   flagp = (int*)carve((size_t)256 * 32 * 4);
  int*   modep = (int*)carve(256);
  size_t part2_bytes = (size_t)T_ * R_ * B_ * O_ * 2;          // 52.4 MB
  u16*   part2 = (u16*)(ws + off);
  int bigpart = (off + part2_bytes) <= ws_size;

  hipMemsetAsync(flagp, 0, (size_t)256 * 32 * 4, stream);

  probe_dtype<<<dim3(1), dim3(256), 0, stream>>>((const u16*)xp, modep);
  conv_split<<<dim3((XOFF + 255)/256), dim3(256), 0, stream>>>(xp, xb, xb + XOFF, modep, XOFF);
  conv_vec<<<dim3((R_*H_ + 255)/256), dim3(256), 0, stream>>>(biasp, biasf, modep, R_*H_);
  conv_vec<<<dim3(1), dim3(256), 0, stream>>>(boutp, boutf, modep, O_);
  conv_vec<<<dim3((R_*R_ + 255)/256), dim3(256), 0, stream>>>(Cp, cfp, modep, R_*R_);

  transpose_kn2<<<dim3(R_ * 16), dim3(256), 0, stream>>>(Wih,  wihT,  wihT  + WOFF, I_, H_, modep, 0);
  transpose_kn2<<<dim3(R_ * 16), dim3(256), 0, stream>>>(Whh,  whhT,  whhT  + WOFF, H_, H_, modep, 0);
  transpose_kn2<<<dim3(R_ * 16), dim3(256), 0, stream>>>(Wrhh, wrhhT, wrhhT + WOFF, H_, H_, modep, 1);
  transpose_kn2<<<dim3(800),     dim3(256), 0, stream>>>(Wout, woutT, woutT + OOFF, R_ * H_, O_, modep, 0);

  // 200 (region, batch-half) WGs x 512 threads; +4 reducers in small mode
  int nblk = bigpart ? NWG2 : (NWG2 + NRED);
  rnn_kernel<<<dim3(nblk), dim3(512), 0, stream>>>(
      xb, Hb, wihT, whhT, wrhhT, cfp, biasf, woutT,
      partp, part2, boutf, outp, flagp, bigpart);

  if (bigpart)
    reduce_out<<<dim3(T_), dim3(256), 0, stream>>>(part2, boutf, outp);
}